// Round 4
// baseline (194.939 us; speedup 1.0000x reference)
//
#include <hip/hip_runtime.h>
#include <math.h>
#include <limits.h>

#define NBINS 15

typedef float f32x4 __attribute__((ext_vector_type(4)));

// ws layout: 45 floats: [bin*3 + 0]=count, [+1]=conf_sum, [+2]=acc_sum
__global__ void ece_zero_ws(float* ws) {
    int i = threadIdx.x;
    if (i < NBINS * 3) ws[i] = 0.0f;
}

// Whole row register-cached, contiguous rows per wave, next-row prefetch.
// NV float4 per lane, NV*64*4 >= C, C%4==0.
template <int NV>
__global__ void __launch_bounds__(256, 4) ece_main_reg(
    const float* __restrict__ logits, const int* __restrict__ labels,
    float* __restrict__ ws, int N, int C) {
    __shared__ float lds[NBINS * 3];
    if (threadIdx.x < NBINS * 3) lds[threadIdx.x] = 0.0f;
    __syncthreads();

    const int lane = threadIdx.x & 63;
    const int wid  = blockIdx.x * (blockDim.x >> 6) + (threadIdx.x >> 6);
    const int nw   = gridDim.x * (blockDim.x >> 6);
    const int nvec = C >> 2;  // float4 chunks per row

    // contiguous chunk of rows per wave (linear HBM stream per wave)
    const int rpw  = (N + nw - 1) / nw;
    const int row0 = wid * rpw;
    const int row1 = (row0 + rpw < N) ? (row0 + rpw) : N;

    f32x4 bufA[NV], bufB[NV];

    auto load_row = [&](int row, f32x4 (&r)[NV]) {
        const f32x4* rp = (const f32x4*)(logits + (size_t)row * (size_t)C);
        #pragma unroll
        for (int j = 0; j < NV; ++j) {
            int idx = lane + j * 64;
            if (idx < nvec) r[j] = __builtin_nontemporal_load(&rp[idx]);
            else            r[j] = (f32x4){-INFINITY, -INFINITY, -INFINITY, -INFINITY};
        }
    };

    auto compute_row = [&](int row, f32x4 (&r)[NV]) {
        // pass 1: exact row max (independent fmax tree)
        float m = -INFINITY;
        #pragma unroll
        for (int j = 0; j < NV; ++j)
            m = fmaxf(m, fmaxf(fmaxf(r[j].x, r[j].y), fmaxf(r[j].z, r[j].w)));
        #pragma unroll
        for (int off = 32; off >= 1; off >>= 1)
            m = fmaxf(m, __shfl_xor(m, off));

        // pass 2: independent exp-sum + first-occurrence argmax
        float s = 0.0f;
        int   mi = INT_MAX;
        #pragma unroll
        for (int j = 0; j < NV; ++j) {
            int gi = (lane + j * 64) << 2;
            float ex = __expf(r[j].x - m);
            float ey = __expf(r[j].y - m);
            float ez = __expf(r[j].z - m);
            float ew = __expf(r[j].w - m);
            s += (ex + ey) + (ez + ew);
            if (r[j].x == m) mi = min(mi, gi);
            if (r[j].y == m) mi = min(mi, gi + 1);
            if (r[j].z == m) mi = min(mi, gi + 2);
            if (r[j].w == m) mi = min(mi, gi + 3);
        }
        #pragma unroll
        for (int off = 32; off >= 1; off >>= 1) {
            s += __shfl_xor(s, off);
            mi = min(mi, __shfl_xor(mi, off));
        }

        if (lane == 0) {
            float conf = 1.0f / s;  // exp(m-m)/sum = max softmax prob
            float acc  = (labels[row] == mi) ? 1.0f : 0.0f;
            int b = (int)ceilf(conf * (float)NBINS) - 1;
            b = b < 0 ? 0 : (b > NBINS - 1 ? NBINS - 1 : b);
            atomicAdd(&lds[b * 3 + 0], 1.0f);
            atomicAdd(&lds[b * 3 + 1], conf);
            atomicAdd(&lds[b * 3 + 2], acc);
        }
    };

    if (row0 < row1) {
        load_row(row0, bufA);
        int row = row0;
        for (;;) {
            // A body: prefetch row+1 into B, compute A
            if (row + 1 < row1) load_row(row + 1, bufB);
            compute_row(row, bufA);
            ++row;
            if (row >= row1) break;
            // B body: prefetch row+1 into A, compute B
            if (row + 1 < row1) load_row(row + 1, bufA);
            compute_row(row, bufB);
            ++row;
            if (row >= row1) break;
        }
    }

    __syncthreads();
    if (threadIdx.x < NBINS * 3) atomicAdd(&ws[threadIdx.x], lds[threadIdx.x]);
}

// Generic fallback (any C): online-softmax version.
__global__ void __launch_bounds__(256, 4) ece_main_gen(
    const float* __restrict__ logits, const int* __restrict__ labels,
    float* __restrict__ ws, int N, int C) {
    __shared__ float lds[NBINS * 3];
    if (threadIdx.x < NBINS * 3) lds[threadIdx.x] = 0.0f;
    __syncthreads();

    const int lane = threadIdx.x & 63;
    const int wid  = blockIdx.x * (blockDim.x >> 6) + (threadIdx.x >> 6);
    const int nw   = gridDim.x * (blockDim.x >> 6);

    for (int row = wid; row < N; row += nw) {
        const float* rp = logits + (size_t)row * (size_t)C;
        float m = -INFINITY;
        float s = 0.0f;
        int   mi = INT_MAX;
        for (int i = lane; i < C; i += 64) {
            float v = rp[i];
            if (v > m) { s = s * __expf(m - v) + 1.0f; m = v; mi = i; }
            else       { s += __expf(v - m); }
        }
        #pragma unroll
        for (int off = 32; off >= 1; off >>= 1) {
            float om  = __shfl_xor(m, off);
            float os  = __shfl_xor(s, off);
            int   omi = __shfl_xor(mi, off);
            float nm  = fmaxf(m, om);
            float e1  = (m  > -INFINITY) ? __expf(m  - nm) : 0.0f;
            float e2  = (om > -INFINITY) ? __expf(om - nm) : 0.0f;
            s = s * e1 + os * e2;
            if (om > m || (om == m && omi < mi)) mi = omi;
            m = nm;
        }
        if (lane == 0) {
            float conf = 1.0f / s;
            float acc  = (labels[row] == mi) ? 1.0f : 0.0f;
            int b = (int)ceilf(conf * (float)NBINS) - 1;
            b = b < 0 ? 0 : (b > NBINS - 1 ? NBINS - 1 : b);
            atomicAdd(&lds[b * 3 + 0], 1.0f);
            atomicAdd(&lds[b * 3 + 1], conf);
            atomicAdd(&lds[b * 3 + 2], acc);
        }
    }

    __syncthreads();
    if (threadIdx.x < NBINS * 3) atomicAdd(&ws[threadIdx.x], lds[threadIdx.x]);
}

__global__ void ece_final(const float* __restrict__ ws, float* __restrict__ out, float n) {
    if (threadIdx.x == 0) {
        float ece = 0.0f;
        #pragma unroll
        for (int b = 0; b < NBINS; ++b) {
            float c  = ws[b * 3 + 0];
            float cs = ws[b * 3 + 1];
            float as = ws[b * 3 + 2];
            if (c > 0.0f) ece += fabsf(cs / c - as / c) * (c / n);
        }
        out[0] = ece;
    }
}

extern "C" void kernel_launch(void* const* d_in, const int* in_sizes, int n_in,
                              void* d_out, int out_size, void* d_ws, size_t ws_size,
                              hipStream_t stream) {
    const float* logits = (const float*)d_in[0];
    const int*   labels = (const int*)d_in[1];
    float* out = (float*)d_out;
    float* ws  = (float*)d_ws;

    const int N = in_sizes[1];
    const int C = in_sizes[0] / in_sizes[1];

    ece_zero_ws<<<1, 64, 0, stream>>>(ws);

    const int threads = 256;
    int blocks = (N + (threads / 64) - 1) / (threads / 64);
    if (blocks > 2048) blocks = 2048;

    if ((C & 3) == 0 && C <= 4 * 64 * 4) {
        // C fits in 4 float4 per lane (C <= 1024), C divisible by 4
        ece_main_reg<4><<<blocks, threads, 0, stream>>>(logits, labels, ws, N, C);
    } else if ((C & 3) == 0 && C <= 8 * 64 * 4) {
        ece_main_reg<8><<<blocks, threads, 0, stream>>>(logits, labels, ws, N, C);
    } else {
        ece_main_gen<<<blocks, threads, 0, stream>>>(logits, labels, ws, N, C);
    }

    ece_final<<<1, 64, 0, stream>>>(ws, out, (float)N);
}

// Round 5
// 184.080 us; speedup vs baseline: 1.0590x; 1.0590x over previous
//
#include <hip/hip_runtime.h>
#include <math.h>
#include <limits.h>

#define NBINS 15

typedef float f32x4 __attribute__((ext_vector_type(4)));

// ws layout: 45 floats: [bin*3 + 0]=count, [+1]=conf_sum, [+2]=acc_sum
__global__ void ece_zero_ws(float* ws) {
    int i = threadIdx.x;
    if (i < NBINS * 3) ws[i] = 0.0f;
}

// Fast path: whole row register-cached. NV float4 per lane, NV*64*4 >= C, C%4==0.
// 8 waves/SIMD (32 waves/CU) to keep HBM queues full across reduce-chain bubbles.
template <int NV>
__global__ void __launch_bounds__(256, 8) ece_main_reg(
    const float* __restrict__ logits, const int* __restrict__ labels,
    float* __restrict__ ws, int N, int C) {
    __shared__ float lds[NBINS * 3];
    if (threadIdx.x < NBINS * 3) lds[threadIdx.x] = 0.0f;
    __syncthreads();

    const int lane = threadIdx.x & 63;
    const int wid  = blockIdx.x * (blockDim.x >> 6) + (threadIdx.x >> 6);
    const int nw   = gridDim.x * (blockDim.x >> 6);
    const int nvec = C >> 2;  // float4 chunks per row

    for (int row = wid; row < N; row += nw) {
        const f32x4* rp = (const f32x4*)(logits + (size_t)row * (size_t)C);

        // ---- load whole row into registers (masked, branch-free fill) ----
        f32x4 r[NV];
        #pragma unroll
        for (int j = 0; j < NV; ++j) {
            int idx = lane + j * 64;
            if (idx < nvec) {
                r[j] = __builtin_nontemporal_load(&rp[idx]);
            } else {
                r[j] = (f32x4){-INFINITY, -INFINITY, -INFINITY, -INFINITY};
            }
        }

        // ---- pass 1: exact row max (independent fmax tree) ----
        float m = -INFINITY;
        #pragma unroll
        for (int j = 0; j < NV; ++j) {
            m = fmaxf(m, fmaxf(fmaxf(r[j].x, r[j].y), fmaxf(r[j].z, r[j].w)));
        }
        #pragma unroll
        for (int off = 32; off >= 1; off >>= 1)
            m = fmaxf(m, __shfl_xor(m, off));

        // ---- pass 2: independent exp-sum + first-occurrence argmax ----
        float s = 0.0f;
        int   mi = INT_MAX;
        #pragma unroll
        for (int j = 0; j < NV; ++j) {
            int gi = (lane + j * 64) << 2;
            float ex = __expf(r[j].x - m);
            float ey = __expf(r[j].y - m);
            float ez = __expf(r[j].z - m);
            float ew = __expf(r[j].w - m);
            s += (ex + ey) + (ez + ew);
            if (r[j].x == m) mi = min(mi, gi);
            if (r[j].y == m) mi = min(mi, gi + 1);
            if (r[j].z == m) mi = min(mi, gi + 2);
            if (r[j].w == m) mi = min(mi, gi + 3);
        }
        #pragma unroll
        for (int off = 32; off >= 1; off >>= 1) {
            s += __shfl_xor(s, off);
            mi = min(mi, __shfl_xor(mi, off));
        }

        if (lane == 0) {
            float conf = 1.0f / s;  // exp(m-m)/sum = max softmax prob
            float acc  = (labels[row] == mi) ? 1.0f : 0.0f;
            int b = (int)ceilf(conf * (float)NBINS) - 1;
            b = b < 0 ? 0 : (b > NBINS - 1 ? NBINS - 1 : b);
            atomicAdd(&lds[b * 3 + 0], 1.0f);
            atomicAdd(&lds[b * 3 + 1], conf);
            atomicAdd(&lds[b * 3 + 2], acc);
        }
    }

    __syncthreads();
    if (threadIdx.x < NBINS * 3) atomicAdd(&ws[threadIdx.x], lds[threadIdx.x]);
}

// Generic fallback (any C): online-softmax version.
__global__ void __launch_bounds__(256, 4) ece_main_gen(
    const float* __restrict__ logits, const int* __restrict__ labels,
    float* __restrict__ ws, int N, int C) {
    __shared__ float lds[NBINS * 3];
    if (threadIdx.x < NBINS * 3) lds[threadIdx.x] = 0.0f;
    __syncthreads();

    const int lane = threadIdx.x & 63;
    const int wid  = blockIdx.x * (blockDim.x >> 6) + (threadIdx.x >> 6);
    const int nw   = gridDim.x * (blockDim.x >> 6);

    for (int row = wid; row < N; row += nw) {
        const float* rp = logits + (size_t)row * (size_t)C;
        float m = -INFINITY;
        float s = 0.0f;
        int   mi = INT_MAX;
        for (int i = lane; i < C; i += 64) {
            float v = rp[i];
            if (v > m) { s = s * __expf(m - v) + 1.0f; m = v; mi = i; }
            else       { s += __expf(v - m); }
        }
        #pragma unroll
        for (int off = 32; off >= 1; off >>= 1) {
            float om  = __shfl_xor(m, off);
            float os  = __shfl_xor(s, off);
            int   omi = __shfl_xor(mi, off);
            float nm  = fmaxf(m, om);
            float e1  = (m  > -INFINITY) ? __expf(m  - nm) : 0.0f;
            float e2  = (om > -INFINITY) ? __expf(om - nm) : 0.0f;
            s = s * e1 + os * e2;
            if (om > m || (om == m && omi < mi)) mi = omi;
            m = nm;
        }
        if (lane == 0) {
            float conf = 1.0f / s;
            float acc  = (labels[row] == mi) ? 1.0f : 0.0f;
            int b = (int)ceilf(conf * (float)NBINS) - 1;
            b = b < 0 ? 0 : (b > NBINS - 1 ? NBINS - 1 : b);
            atomicAdd(&lds[b * 3 + 0], 1.0f);
            atomicAdd(&lds[b * 3 + 1], conf);
            atomicAdd(&lds[b * 3 + 2], acc);
        }
    }

    __syncthreads();
    if (threadIdx.x < NBINS * 3) atomicAdd(&ws[threadIdx.x], lds[threadIdx.x]);
}

__global__ void ece_final(const float* __restrict__ ws, float* __restrict__ out, float n) {
    if (threadIdx.x == 0) {
        float ece = 0.0f;
        #pragma unroll
        for (int b = 0; b < NBINS; ++b) {
            float c  = ws[b * 3 + 0];
            float cs = ws[b * 3 + 1];
            float as = ws[b * 3 + 2];
            if (c > 0.0f) ece += fabsf(cs / c - as / c) * (c / n);
        }
        out[0] = ece;
    }
}

extern "C" void kernel_launch(void* const* d_in, const int* in_sizes, int n_in,
                              void* d_out, int out_size, void* d_ws, size_t ws_size,
                              hipStream_t stream) {
    const float* logits = (const float*)d_in[0];
    const int*   labels = (const int*)d_in[1];
    float* out = (float*)d_out;
    float* ws  = (float*)d_ws;

    const int N = in_sizes[1];
    const int C = in_sizes[0] / in_sizes[1];

    ece_zero_ws<<<1, 64, 0, stream>>>(ws);

    const int threads = 256;
    int blocks = (N + (threads / 64) - 1) / (threads / 64);
    if (blocks > 2048) blocks = 2048;

    if ((C & 3) == 0 && C <= 4 * 64 * 4) {
        // C fits in 4 float4 per lane (C <= 1024), C divisible by 4
        ece_main_reg<4><<<blocks, threads, 0, stream>>>(logits, labels, ws, N, C);
    } else if ((C & 3) == 0 && C <= 8 * 64 * 4) {
        ece_main_reg<8><<<blocks, threads, 0, stream>>>(logits, labels, ws, N, C);
    } else {
        ece_main_gen<<<blocks, threads, 0, stream>>>(logits, labels, ws, N, C);
    }

    ece_final<<<1, 64, 0, stream>>>(ws, out, (float)N);
}